// Round 4
// baseline (402.184 us; speedup 1.0000x reference)
//
#include <hip/hip_runtime.h>
#include <cstdint>

// ---------------------------------------------------------------------------
// dysOpt: Davis-Yin splitting, 262144 rows x 64 vars, dynamic T.
//
// x20 u-space iteration (U = 20*(z + C), CC = 20*C):
//   m'  = med3(U, CC, CC+20)      (= 20*(clamp(z,0,1)+C)), computed IN PLACE
//   U+  = K1*m' + nc[j]           (nc = -c, stored negated)
//   Sx  = 0.05*(Sm' - 64*CC) ; t = K2*Sx - R
//   corr20 = t*(20/64) - 10 ; R+ = R - Sx + 32 ; CC+ = K1*CC + corr20
// Exact algebra vs reference; rescale rounding ~1 ulp/iter damped by the
// K1 = 0.9975 contraction.
//
// ROUND-14 (pin the occupancy target; r13 post-mortem):
//  * r11 (asm arrays), r12 (IR arrays), r13 (named SSA vars) ALL compile to
//    VGPR_Count=76 exactly. Named vars cannot fail SROA => the scratch is
//    NOT a promotion failure. The backend CHOSE 76 regs: the AMDGPU
//    scheduler's occupancy heuristic (perf-hint tags the kernel memory-
//    bound) targets ~6-7 waves/EU on the 512-reg/SIMD pool (512/6.7 = 76)
//    and spills ~70 floats of loop state to scratch to get there.
//    __launch_bounds__(256,2) sets only a MINIMUM waves/EU — no upper clamp.
//    Evidence: WRITE_SIZE 230MB scratch write-back, VALUBusy 70, dur 265us.
//  * Fix: __attribute__((amdgpu_waves_per_eu(2,2))) — min=max=2 pins the
//    target; register budget = 512/2 = 256 >= demand (~170). Scheduler can
//    no longer trade registers for occupancy. No arithmetic change vs r13.
//  * Falsifiable: VGPR_Count must jump to 150-200 and WRITE_SIZE drop to
//    ~67MB (zst only). If VGPR stays 76, theory is wrong -> layout C
//    (2 lanes/row, 64-float state) next.
//  * probe kernel BYTE-IDENTICAL (layout A, register-resident, fine).
//
// Structure: probe (8192 rows, checked every iter) -> Ts = max Tr <= T;
// pass1: P = Ts-2 unchecked iters, then checked to wave all-pass = ib
// (residual monotone per row => ib = max(P+1, wave-max Tr) <= T, the argmax
// wave reports exactly T); checkpoint z(ib), atomicMax T.
// pass2: resume ib -> T, +1 differentiable step, clamp, store.
// Check (per row, fully in-lane in layout B):
//   400*||dz||^2 = q2 - 2*dCC*q1 + 64*dCC^2 <= 400*TOL^2 = 0.04.
// ---------------------------------------------------------------------------

#ifndef JAX_PARTITIONABLE
#define JAX_PARTITIONABLE 1
#endif

#define BATCHN 262144
#define MAXIT  200

// layout A (probe only): 16 rows/wave, 4 lanes/row, 16 elems/lane
#define RPW_A  16
#define PROBE_ROWS 8192
#define PROBE_WAVES (PROBE_ROWS / RPW_A)    // 512
#define NWAVES_A (BATCHN / RPW_A)           // 16384 (workspace offset compat)

// layout B (pass1/pass2): 64 rows/wave, 1 lane/row, 64 elems/lane
#define RPW_B  64
#define NWAVES_B (BATCHN / RPW_B)           // 4096

#define K1 0.9975f   // 1 - a^2
#define K2 1.9975f   // 2 - a^2

typedef float v2f __attribute__((ext_vector_type(2)));

__device__ __forceinline__ void tf2x32(uint32_t x0, uint32_t x1,
                                       uint32_t& o0, uint32_t& o1) {
  const uint32_t k0 = 0u, k1 = 1u;                 // jax.random.key(1) -> [0,1]
  const uint32_t k2 = 0x1BD11BDAu ^ k0 ^ k1;
  x0 += k0; x1 += k1;
#define TFR(r) { x0 += x1; x1 = (x1 << (r)) | (x1 >> (32 - (r))); x1 ^= x0; }
  TFR(13) TFR(15) TFR(26) TFR(6)   x0 += k1; x1 += k2 + 1u;
  TFR(17) TFR(29) TFR(16) TFR(24)  x0 += k2; x1 += k0 + 2u;
  TFR(13) TFR(15) TFR(26) TFR(6)   x0 += k0; x1 += k1 + 3u;
  TFR(17) TFR(29) TFR(16) TFR(24)  x0 += k1; x1 += k2 + 4u;
  TFR(13) TFR(15) TFR(26) TFR(6)   x0 += k2; x1 += k0 + 5u;
#undef TFR
  o0 = x0; o1 = x1;
}

__device__ __forceinline__ float z0_at(uint32_t f) {
  uint32_t b;
#if JAX_PARTITIONABLE
  uint32_t o0, o1;
  tf2x32(0u, f, o0, o1);
  b = o0 ^ o1;
#else
  const uint32_t H = 8388608u;
  uint32_t lo = (f < H) ? f : (f - H);
  uint32_t o0, o1;
  tf2x32(lo, lo + H, o0, o1);
  b = (f < H) ? o0 : o1;
#endif
  return __uint_as_float((b >> 9) | 0x3f800000u) - 1.0f;
}

// ===========================================================================
// layout A helpers — used ONLY by the probe kernel (kept identical to r10)
// ===========================================================================

// DPP cross-lane add within a quad: v += v(lane DPP-selected). Pure VALU.
template <int CTRL>
__device__ __forceinline__ float dpp_add(float v) {
  int s = __builtin_amdgcn_mov_dpp(__float_as_int(v), CTRL, 0xF, 0xF, true);
  return v + __int_as_float(s);
}

// 4-lane row reduction (row = one quad), all-VALU
__device__ __forceinline__ float reduce4(float v) {
  v = dpp_add<0xB1>(v);    // quad_perm [1,0,3,2] : xor 1
  v = dpp_add<0x4E>(v);    // quad_perm [2,3,0,1] : xor 2
  return v;
}

// checked iteration (A): returns 400*||dz_row||^2 (replicated in the row)
__device__ __forceinline__ float chk_iter_A(float U[16], const float c[16],
                                            float& CC, float& R) {
  const float Ch = CC + 20.0f;
  float sp[4] = {0.0f, 0.0f, 0.0f, 0.0f};
  float q1a = 0.0f, q1b = 0.0f, q2a = 0.0f, q2b = 0.0f;
#pragma unroll
  for (int j = 0; j < 16; ++j) {
    float m = __builtin_amdgcn_fmed3f(U[j], CC, Ch);
    sp[j & 3] += m;
    float un = __builtin_fmaf(K1, m, -c[j]);
    float d = un - U[j];
    if (j & 1) { q1b += d; q2b = __builtin_fmaf(d, d, q2b); }
    else       { q1a += d; q2a = __builtin_fmaf(d, d, q2a); }
    U[j] = un;
  }
  float s = (sp[0] + sp[1]) + (sp[2] + sp[3]);
  s = reduce4(s);
  float Sx = 0.05f * __builtin_fmaf(-64.0f, CC, s);
  float t  = __builtin_fmaf(K2, Sx, -R);
  float corr20 = __builtin_fmaf(t, 0.3125f, -10.0f);
  R = (R - Sx) + 32.0f;
  float CCn = __builtin_fmaf(K1, CC, corr20);
  float dCC = CCn - CC;
  CC = CCn;
  float q1 = reduce4(q1a + q1b);
  float q2 = reduce4(q2a + q2b);
  // 400*ds = q2 - 2*dCC*q1 + 64*dCC^2
  float a = __builtin_fmaf(64.0f, dCC, -2.0f * q1);
  return __builtin_fmaf(dCC, a, q2);
}

__device__ __forceinline__ void load_c_A(const float* __restrict__ cost,
                                         int base, float c[16]) {
#pragma unroll
  for (int k = 0; k < 4; ++k) {
    const float4 cq = *(const float4*)(cost + base + 4 * k);
    c[4 * k + 0] = cq.x; c[4 * k + 1] = cq.y;
    c[4 * k + 2] = cq.z; c[4 * k + 3] = cq.w;
  }
}

// Pin value to a VGPR: asm-defined => compiler cannot remat via reload.
// (layout A only)
__device__ __forceinline__ void pin16(float v[16]) {
#pragma unroll
  for (int j = 0; j < 16; ++j) asm("" : "+v"(v[j]));
}

__device__ __forceinline__ void init_state_A(const float* __restrict__ cost,
                                             int base, float c[16],
                                             float U[16], float& CC,
                                             float& R) {
  load_c_A(cost, base, c);
  float r = 0.0f;
#pragma unroll
  for (int j = 0; j < 16; ++j) {
    float z0 = z0_at((uint32_t)(base + j));
    U[j] = 20.0f * z0;
    r = __builtin_fmaf(0.05f, c[j], r + z0);   // r += z0 + 0.05*c
  }
  pin16(c);
  pin16(U);
  R = reduce4(r);                               // R = Sz + a*Sc
  CC = 0.0f;
}

// --- probe: rows [0, PROBE_ROWS), checked every iter, atomicMax Ts ---------
__global__ __launch_bounds__(256, 4) void dys_probe(
    const float* __restrict__ cost, int* __restrict__ Tsample) {
  const int lane = threadIdx.x & 63;
  const int gw = blockIdx.x * 4 + (threadIdx.x >> 6);
  const int base = (gw * RPW_A + (lane >> 2)) * 64 + (lane & 3) * 16;

  float c[16], U[16], CC, R;
  init_state_A(cost, base, c, U, CC, R);

  int ib = MAXIT;
  for (int i = 1; i <= MAXIT; ++i) {
    float ds = chk_iter_A(U, c, CC, R);
    if (__all(ds <= 0.04f)) { ib = i; break; }   // wave-max Tr
  }
  if (lane == 0) atomicMax(Tsample, ib);
}

// ===========================================================================
// layout B — 1 lane = 1 row; 64 NAMED v2f variables (no arrays, no allocas);
// occupancy pinned via amdgpu_waves_per_eu(2,2) => 256-VGPR budget
// ===========================================================================

#define P32(X) X(0) X(1) X(2) X(3) X(4) X(5) X(6) X(7) X(8) X(9) X(10) X(11) \
  X(12) X(13) X(14) X(15) X(16) X(17) X(18) X(19) X(20) X(21) X(22) X(23) \
  X(24) X(25) X(26) X(27) X(28) X(29) X(30) X(31)

#define PAIRS(X) X(0,0,1) X(1,2,3) X(2,4,5) X(3,6,7) X(4,8,9) X(5,10,11) \
  X(6,12,13) X(7,14,15) X(8,16,17) X(9,18,19) X(10,20,21) X(11,22,23) \
  X(12,24,25) X(13,26,27) X(14,28,29) X(15,30,31)

// state declaration: U0..U31, nc0..nc31 (each v2f = one even-aligned VGPR pair)
#define DECL_STATE(p) v2f U##p, nc##p;

// load cost, negated: nc = -c
#define LOADC(k, p0, p1) { \
  const float4 cq = *(const float4*)(cost + base + 4 * (k)); \
  nc##p0.x = -cq.x; nc##p0.y = -cq.y; nc##p1.x = -cq.z; nc##p1.y = -cq.w; }

// init U from threefry z0; accumulate R partials
#define INITU(p) { \
  const float za = z0_at((uint32_t)(base + 2 * (p))); \
  const float zb = z0_at((uint32_t)(base + 2 * (p) + 1)); \
  U##p.x = 20.0f * za; U##p.y = 20.0f * zb; \
  r0 = __builtin_fmaf(-0.05f, nc##p.x, r0 + za); \
  r1 = __builtin_fmaf(-0.05f, nc##p.y, r1 + zb); }

// fast step: 2 med3 + 1 pk_add + 1 pk_fma per pair
#define FSTEP(p) { v2f m2; \
  m2.x = __builtin_amdgcn_fmed3f(U##p.x, CC, Ch); \
  m2.y = __builtin_amdgcn_fmed3f(U##p.y, CC, Ch); \
  if ((p) & 1) spB += m2; else spA += m2; \
  U##p = __builtin_elementwise_fma(K1p, m2, nc##p); }

#define FAST_ITER() { \
  const float Ch = CC + 20.0f; \
  v2f spA = {0.0f, 0.0f}, spB = {0.0f, 0.0f}; \
  P32(FSTEP) \
  const v2f spc = spA + spB; \
  const float s_ = spc.x + spc.y; \
  const float Sx = 0.05f * __builtin_fmaf(-64.0f, CC, s_); \
  const float t_ = __builtin_fmaf(K2, Sx, -R); \
  const float corr20 = __builtin_fmaf(t_, 0.3125f, -10.0f); \
  R = (R - Sx) + 32.0f; \
  CC = __builtin_fmaf(K1, CC, corr20); }

// checked step: adds d, d^2 accumulation
#define CSTEP(p) { v2f m2; \
  m2.x = __builtin_amdgcn_fmed3f(U##p.x, CC, Ch); \
  m2.y = __builtin_amdgcn_fmed3f(U##p.y, CC, Ch); \
  if ((p) & 1) spB += m2; else spA += m2; \
  const v2f un2 = __builtin_elementwise_fma(K1p, m2, nc##p); \
  const v2f d2 = un2 - U##p; \
  q1v += d2; \
  q2v = __builtin_elementwise_fma(d2, d2, q2v); \
  U##p = un2; }

#define CHK_ITER(DS) { \
  const float Ch = CC + 20.0f; \
  v2f spA = {0.0f, 0.0f}, spB = {0.0f, 0.0f}; \
  v2f q1v = {0.0f, 0.0f}, q2v = {0.0f, 0.0f}; \
  P32(CSTEP) \
  const v2f spc = spA + spB; \
  const float s_ = spc.x + spc.y; \
  const float Sx = 0.05f * __builtin_fmaf(-64.0f, CC, s_); \
  const float t_ = __builtin_fmaf(K2, Sx, -R); \
  const float corr20 = __builtin_fmaf(t_, 0.3125f, -10.0f); \
  R = (R - Sx) + 32.0f; \
  const float CCn = __builtin_fmaf(K1, CC, corr20); \
  const float dCC = CCn - CC; CC = CCn; \
  const float q1 = q1v.x + q1v.y; \
  const float q2 = q2v.x + q2v.y; \
  const float a_ = __builtin_fmaf(64.0f, dCC, -2.0f * q1); \
  DS = __builtin_fmaf(dCC, a_, q2); }

// store z checkpoint: z = 0.05*U - 0.05*CC
#define STZ(k, p0, p1) { float4 zq; \
  zq.x = __builtin_fmaf(0.05f, U##p0.x, -CC05); \
  zq.y = __builtin_fmaf(0.05f, U##p0.y, -CC05); \
  zq.z = __builtin_fmaf(0.05f, U##p1.x, -CC05); \
  zq.w = __builtin_fmaf(0.05f, U##p1.y, -CC05); \
  *(float4*)(zst + base + 4 * (k)) = zq; }

// pass2: load z checkpoint, accumulate R partials
#define LOADZ(k, p0, p1) { \
  const float4 zq = *(const float4*)(zst + base + 4 * (k)); \
  U##p0.x = 20.0f * zq.x; U##p0.y = 20.0f * zq.y; \
  U##p1.x = 20.0f * zq.z; U##p1.y = 20.0f * zq.w; \
  r0 += zq.x + zq.y; r1 += zq.z + zq.w; }

// pass2: R += 0.05*c
#define RC(p) { r0 = __builtin_fmaf(-0.05f, nc##p.x, r0); \
  r1 = __builtin_fmaf(-0.05f, nc##p.y, r1); }

// final store: clamp(z, 0, 1)
#define STOUT(k, p0, p1) { float4 o; \
  o.x = __builtin_amdgcn_fmed3f( \
      __builtin_fmaf(0.05f, U##p0.x, -CC05), 0.0f, 1.0f); \
  o.y = __builtin_amdgcn_fmed3f( \
      __builtin_fmaf(0.05f, U##p0.y, -CC05), 0.0f, 1.0f); \
  o.z = __builtin_amdgcn_fmed3f( \
      __builtin_fmaf(0.05f, U##p1.x, -CC05), 0.0f, 1.0f); \
  o.w = __builtin_amdgcn_fmed3f( \
      __builtin_fmaf(0.05f, U##p1.y, -CC05), 0.0f, 1.0f); \
  *(float4*)(out + base + 4 * (k)) = o; }

// --- pass1: P unchecked iters, checked to wave all-pass; checkpoint --------
__global__ __attribute__((amdgpu_flat_work_group_size(256, 256),
                          amdgpu_waves_per_eu(2, 2)))
void dys_pass1(
    const float* __restrict__ cost, const int* __restrict__ Tsample,
    int* __restrict__ Tglob, int* __restrict__ TrArr,
    float* __restrict__ zst) {
  const int lane = threadIdx.x & 63;
  const int gw = blockIdx.x * 4 + (threadIdx.x >> 6);
  const int base = (gw * RPW_B + lane) * 64;     // lane owns one full row

  const v2f K1p = {K1, K1};
  P32(DECL_STATE)
  PAIRS(LOADC)
  float r0 = 0.0f, r1 = 0.0f;
  P32(INITU)
  float R = r0 + r1;                       // R = Sz + a*Sc, in-lane
  float CC = 0.0f;

  const int Ts = *Tsample;                 // uniform
  const int Pn = (Ts > 2) ? (Ts - 2) : 0;  // P+1 <= Ts <= T

  for (int i = 0; i < Pn; ++i) FAST_ITER();

  int ib = MAXIT;
  for (int i = Pn + 1; i <= MAXIT; ++i) {
    float ds;
    CHK_ITER(ds)
    if (__all(ds <= 0.04f)) { ib = i; break; }
  }
  // ib = max(Pn+1, wave-max Tr) <= T; the argmax wave reports exactly T.

  const float CC05 = 0.05f * CC;           // z = 0.05*U - 0.05*CC
  PAIRS(STZ)
  if (lane == 0) {
    TrArr[gw] = ib;
    atomicMax(Tglob, ib);
  }
}

// --- pass2: resume ib -> T, +1 differentiable step, clamp, store -----------
__global__ __attribute__((amdgpu_flat_work_group_size(256, 256),
                          amdgpu_waves_per_eu(2, 2)))
void dys_pass2(
    const float* __restrict__ cost, const int* __restrict__ Tglob,
    const int* __restrict__ TrArr, const float* __restrict__ zst,
    float* __restrict__ out) {
  const int lane = threadIdx.x & 63;
  const int gw = blockIdx.x * 4 + (threadIdx.x >> 6);
  const int base = (gw * RPW_B + lane) * 64;

  const v2f K1p = {K1, K1};
  P32(DECL_STATE)
  PAIRS(LOADC)
  float r0 = 0.0f, r1 = 0.0f;
  PAIRS(LOADZ)
  P32(RC)
  float R = r0 + r1;                       // R = Sz + a*Sc (invariant)
  float CC = 0.0f;

  const int T = *Tglob;
  const int ib = TrArr[gw];                // wave-uniform

  // (T - ib) lockstep iters to z(T), +1 differentiable step
  for (int i = ib; i <= T; ++i) FAST_ITER();

  const float CC05 = 0.05f * CC;
  PAIRS(STOUT)
}

extern "C" void kernel_launch(void* const* d_in, const int* in_sizes, int n_in,
                              void* d_out, int out_size, void* d_ws,
                              size_t ws_size, hipStream_t stream) {
  const float* cost = (const float*)d_in[0];
  float* out = (float*)d_out;

  // ws: [0..4) Tglob ; [4..8) Tsample ; [1024..) TrArr ; then z ckpt
  // (offsets kept from r10: TrArr region sized for 16384 ints, B uses 4096)
  int* Tglob   = (int*)d_ws;
  int* Tsample = (int*)d_ws + 1;
  const size_t TR_OFF = 1024;
  const size_t Z_OFF  = TR_OFF + (size_t)NWAVES_A * sizeof(int);  // 16B-aligned
  int*   TrArr = (int*)((char*)d_ws + TR_OFF);
  float* zst   = (float*)((char*)d_ws + Z_OFF);

  hipMemsetAsync(d_ws, 0, 8, stream);   // Tglob = Tsample = 0

  dim3 block(256);
  dys_probe<<<dim3(PROBE_WAVES / 4), block, 0, stream>>>(cost, Tsample);
  dys_pass1<<<dim3(NWAVES_B / 4), block, 0, stream>>>(cost, Tsample, Tglob,
                                                      TrArr, zst);
  dys_pass2<<<dim3(NWAVES_B / 4), block, 0, stream>>>(cost, Tglob, TrArr, zst,
                                                      out);
}

// Round 5
// 369.423 us; speedup vs baseline: 1.0887x; 1.0887x over previous
//
#include <hip/hip_runtime.h>
#include <cstdint>

// ---------------------------------------------------------------------------
// dysOpt: Davis-Yin splitting, 262144 rows x 64 vars, dynamic T.
//
// x20 u-space iteration (U = 20*(z + C), CC = 20*C):
//   m'  = med3(U, CC, CC+20)      (= 20*(clamp(z,0,1)+C)), computed IN PLACE
//   U+  = K1*m' + nc[j]           (nc = -c, stored negated)
//   Sx  = 0.05*(Sm' - 64*CC) ; t = K2*Sx - R
//   corr20 = t*(20/64) - 10 ; R+ = R - Sx + 32 ; CC+ = K1*CC + corr20
// Exact algebra vs reference; rescale rounding ~1 ulp/iter damped by the
// K1 = 0.9975 contraction.
//
// ROUND-15 (fit under the allocator's empirical cap; r14 post-mortem):
//  * r14 pinned waves_per_eu(2,2): VGPR 76->88, dur 265->230, but WRITE_SIZE
//    still ~175MB => the backend spills half the 128-float state EVEN WITH a
//    256-reg budget. Four source forms + two attribute sets all cap at
//    76-88 VGPR. Conclusion: demand must fit UNDER ~88, not fight it.
//  * Layout C: 2 lanes/row, 32 elems/lane, 32 rows/wave. State = 64 floats
//    (16 v2f U + 16 v2f nc) + ~20 temps ~= 84-90 demand. Row reduction =
//    ONE dpp_add (lane^1). 78 instr/wave-iter for 32 rows = 2.4/row-iter
//    (layout A: 3.94 at 276us => predict ~170us).
//  * waves_per_eu(4,4): budget 512/4 = 128 >= demand; 4 waves/EU occupancy.
//  * Falsifiable: VGPR ~90-100 AND WRITE_SIZE ~67MB (zst only) = resident.
//    If VGPR <=88 with WRITE_SIZE >120MB again -> fall back to packed
//    layout A (demand ~45) next round.
//  * probe kernel BYTE-IDENTICAL (layout A, register-resident, fine).
//
// Structure: probe (8192 rows, checked every iter) -> Ts = max Tr <= T;
// pass1: P = Ts-2 unchecked iters, then checked to wave all-pass = ib
// (residual monotone per row => ib = max(P+1, wave-max Tr) <= T, the argmax
// wave reports exactly T); checkpoint z(ib), atomicMax T.
// pass2: resume ib -> T, +1 differentiable step, clamp, store.
// Check (per row, 2 lanes): 400*||dz||^2 = q2 - 2*dCC*q1 + 64*dCC^2 <= 0.04.
// ---------------------------------------------------------------------------

#ifndef JAX_PARTITIONABLE
#define JAX_PARTITIONABLE 1
#endif

#define BATCHN 262144
#define MAXIT  200

// layout A (probe only): 16 rows/wave, 4 lanes/row, 16 elems/lane
#define RPW_A  16
#define PROBE_ROWS 8192
#define PROBE_WAVES (PROBE_ROWS / RPW_A)    // 512
#define NWAVES_A (BATCHN / RPW_A)           // 16384 (workspace offset compat)

// layout C (pass1/pass2): 32 rows/wave, 2 lanes/row, 32 elems/lane
#define RPW_C  32
#define NWAVES_C (BATCHN / RPW_C)           // 8192

#define K1 0.9975f   // 1 - a^2
#define K2 1.9975f   // 2 - a^2

typedef float v2f __attribute__((ext_vector_type(2)));

__device__ __forceinline__ void tf2x32(uint32_t x0, uint32_t x1,
                                       uint32_t& o0, uint32_t& o1) {
  const uint32_t k0 = 0u, k1 = 1u;                 // jax.random.key(1) -> [0,1]
  const uint32_t k2 = 0x1BD11BDAu ^ k0 ^ k1;
  x0 += k0; x1 += k1;
#define TFR(r) { x0 += x1; x1 = (x1 << (r)) | (x1 >> (32 - (r))); x1 ^= x0; }
  TFR(13) TFR(15) TFR(26) TFR(6)   x0 += k1; x1 += k2 + 1u;
  TFR(17) TFR(29) TFR(16) TFR(24)  x0 += k2; x1 += k0 + 2u;
  TFR(13) TFR(15) TFR(26) TFR(6)   x0 += k0; x1 += k1 + 3u;
  TFR(17) TFR(29) TFR(16) TFR(24)  x0 += k1; x1 += k2 + 4u;
  TFR(13) TFR(15) TFR(26) TFR(6)   x0 += k2; x1 += k0 + 5u;
#undef TFR
  o0 = x0; o1 = x1;
}

__device__ __forceinline__ float z0_at(uint32_t f) {
  uint32_t b;
#if JAX_PARTITIONABLE
  uint32_t o0, o1;
  tf2x32(0u, f, o0, o1);
  b = o0 ^ o1;
#else
  const uint32_t H = 8388608u;
  uint32_t lo = (f < H) ? f : (f - H);
  uint32_t o0, o1;
  tf2x32(lo, lo + H, o0, o1);
  b = (f < H) ? o0 : o1;
#endif
  return __uint_as_float((b >> 9) | 0x3f800000u) - 1.0f;
}

// DPP cross-lane add within a quad: v += v(lane DPP-selected). Pure VALU.
template <int CTRL>
__device__ __forceinline__ float dpp_add(float v) {
  int s = __builtin_amdgcn_mov_dpp(__float_as_int(v), CTRL, 0xF, 0xF, true);
  return v + __int_as_float(s);
}

// 4-lane row reduction (row = one quad), all-VALU (layout A)
__device__ __forceinline__ float reduce4(float v) {
  v = dpp_add<0xB1>(v);    // quad_perm [1,0,3,2] : xor 1
  v = dpp_add<0x4E>(v);    // quad_perm [2,3,0,1] : xor 2
  return v;
}

// 2-lane row reduction (row = lane pair), single DPP (layout C)
__device__ __forceinline__ float reduce2(float v) {
  return dpp_add<0xB1>(v); // quad_perm [1,0,3,2] : xor 1
}

// ===========================================================================
// layout A helpers — used ONLY by the probe kernel (kept identical to r10)
// ===========================================================================

// checked iteration (A): returns 400*||dz_row||^2 (replicated in the row)
__device__ __forceinline__ float chk_iter_A(float U[16], const float c[16],
                                            float& CC, float& R) {
  const float Ch = CC + 20.0f;
  float sp[4] = {0.0f, 0.0f, 0.0f, 0.0f};
  float q1a = 0.0f, q1b = 0.0f, q2a = 0.0f, q2b = 0.0f;
#pragma unroll
  for (int j = 0; j < 16; ++j) {
    float m = __builtin_amdgcn_fmed3f(U[j], CC, Ch);
    sp[j & 3] += m;
    float un = __builtin_fmaf(K1, m, -c[j]);
    float d = un - U[j];
    if (j & 1) { q1b += d; q2b = __builtin_fmaf(d, d, q2b); }
    else       { q1a += d; q2a = __builtin_fmaf(d, d, q2a); }
    U[j] = un;
  }
  float s = (sp[0] + sp[1]) + (sp[2] + sp[3]);
  s = reduce4(s);
  float Sx = 0.05f * __builtin_fmaf(-64.0f, CC, s);
  float t  = __builtin_fmaf(K2, Sx, -R);
  float corr20 = __builtin_fmaf(t, 0.3125f, -10.0f);
  R = (R - Sx) + 32.0f;
  float CCn = __builtin_fmaf(K1, CC, corr20);
  float dCC = CCn - CC;
  CC = CCn;
  float q1 = reduce4(q1a + q1b);
  float q2 = reduce4(q2a + q2b);
  // 400*ds = q2 - 2*dCC*q1 + 64*dCC^2
  float a = __builtin_fmaf(64.0f, dCC, -2.0f * q1);
  return __builtin_fmaf(dCC, a, q2);
}

__device__ __forceinline__ void load_c_A(const float* __restrict__ cost,
                                         int base, float c[16]) {
#pragma unroll
  for (int k = 0; k < 4; ++k) {
    const float4 cq = *(const float4*)(cost + base + 4 * k);
    c[4 * k + 0] = cq.x; c[4 * k + 1] = cq.y;
    c[4 * k + 2] = cq.z; c[4 * k + 3] = cq.w;
  }
}

// Pin value to a VGPR: asm-defined => compiler cannot remat via reload.
// (layout A only)
__device__ __forceinline__ void pin16(float v[16]) {
#pragma unroll
  for (int j = 0; j < 16; ++j) asm("" : "+v"(v[j]));
}

__device__ __forceinline__ void init_state_A(const float* __restrict__ cost,
                                             int base, float c[16],
                                             float U[16], float& CC,
                                             float& R) {
  load_c_A(cost, base, c);
  float r = 0.0f;
#pragma unroll
  for (int j = 0; j < 16; ++j) {
    float z0 = z0_at((uint32_t)(base + j));
    U[j] = 20.0f * z0;
    r = __builtin_fmaf(0.05f, c[j], r + z0);   // r += z0 + 0.05*c
  }
  pin16(c);
  pin16(U);
  R = reduce4(r);                               // R = Sz + a*Sc
  CC = 0.0f;
}

// --- probe: rows [0, PROBE_ROWS), checked every iter, atomicMax Ts ---------
__global__ __launch_bounds__(256, 4) void dys_probe(
    const float* __restrict__ cost, int* __restrict__ Tsample) {
  const int lane = threadIdx.x & 63;
  const int gw = blockIdx.x * 4 + (threadIdx.x >> 6);
  const int base = (gw * RPW_A + (lane >> 2)) * 64 + (lane & 3) * 16;

  float c[16], U[16], CC, R;
  init_state_A(cost, base, c, U, CC, R);

  int ib = MAXIT;
  for (int i = 1; i <= MAXIT; ++i) {
    float ds = chk_iter_A(U, c, CC, R);
    if (__all(ds <= 0.04f)) { ib = i; break; }   // wave-max Tr
  }
  if (lane == 0) atomicMax(Tsample, ib);
}

// ===========================================================================
// layout C — 2 lanes/row, 32 elems/lane; 32 NAMED v2f variables; demand ~86
// fits under the allocator's empirical ~88-reg cap AND the (4,4) 128 budget
// ===========================================================================

#define P16(X) X(0) X(1) X(2) X(3) X(4) X(5) X(6) X(7) X(8) X(9) X(10) X(11) \
  X(12) X(13) X(14) X(15)

#define PAIRS8(X) X(0,0,1) X(1,2,3) X(2,4,5) X(3,6,7) X(4,8,9) X(5,10,11) \
  X(6,12,13) X(7,14,15)

// state declaration: U0..U15, nc0..nc15 (each v2f = one even-aligned pair)
#define DECL_STATE(p) v2f U##p, nc##p;

// load cost, negated: nc = -c
#define LOADC(k, p0, p1) { \
  const float4 cq = *(const float4*)(cost + base + 4 * (k)); \
  nc##p0.x = -cq.x; nc##p0.y = -cq.y; nc##p1.x = -cq.z; nc##p1.y = -cq.w; }

// init U from threefry z0; accumulate R partials
#define INITU(p) { \
  const float za = z0_at((uint32_t)(base + 2 * (p))); \
  const float zb = z0_at((uint32_t)(base + 2 * (p) + 1)); \
  U##p.x = 20.0f * za; U##p.y = 20.0f * zb; \
  r0 = __builtin_fmaf(-0.05f, nc##p.x, r0 + za); \
  r1 = __builtin_fmaf(-0.05f, nc##p.y, r1 + zb); }

// fast step: 2 med3 + 1 pk_add + 1 pk_fma per pair
#define FSTEP(p) { v2f m2; \
  m2.x = __builtin_amdgcn_fmed3f(U##p.x, CC, Ch); \
  m2.y = __builtin_amdgcn_fmed3f(U##p.y, CC, Ch); \
  if ((p) & 1) spB += m2; else spA += m2; \
  U##p = __builtin_elementwise_fma(K1p, m2, nc##p); }

#define FAST_ITER() { \
  const float Ch = CC + 20.0f; \
  v2f spA = {0.0f, 0.0f}, spB = {0.0f, 0.0f}; \
  P16(FSTEP) \
  const v2f spc = spA + spB; \
  const float s_ = reduce2(spc.x + spc.y); \
  const float Sx = 0.05f * __builtin_fmaf(-64.0f, CC, s_); \
  const float t_ = __builtin_fmaf(K2, Sx, -R); \
  const float corr20 = __builtin_fmaf(t_, 0.3125f, -10.0f); \
  R = (R - Sx) + 32.0f; \
  CC = __builtin_fmaf(K1, CC, corr20); }

// checked step: adds d, d^2 accumulation
#define CSTEP(p) { v2f m2; \
  m2.x = __builtin_amdgcn_fmed3f(U##p.x, CC, Ch); \
  m2.y = __builtin_amdgcn_fmed3f(U##p.y, CC, Ch); \
  if ((p) & 1) spB += m2; else spA += m2; \
  const v2f un2 = __builtin_elementwise_fma(K1p, m2, nc##p); \
  const v2f d2 = un2 - U##p; \
  q1v += d2; \
  q2v = __builtin_elementwise_fma(d2, d2, q2v); \
  U##p = un2; }

#define CHK_ITER(DS) { \
  const float Ch = CC + 20.0f; \
  v2f spA = {0.0f, 0.0f}, spB = {0.0f, 0.0f}; \
  v2f q1v = {0.0f, 0.0f}, q2v = {0.0f, 0.0f}; \
  P16(CSTEP) \
  const v2f spc = spA + spB; \
  const float s_ = reduce2(spc.x + spc.y); \
  const float Sx = 0.05f * __builtin_fmaf(-64.0f, CC, s_); \
  const float t_ = __builtin_fmaf(K2, Sx, -R); \
  const float corr20 = __builtin_fmaf(t_, 0.3125f, -10.0f); \
  R = (R - Sx) + 32.0f; \
  const float CCn = __builtin_fmaf(K1, CC, corr20); \
  const float dCC = CCn - CC; CC = CCn; \
  const float q1 = reduce2(q1v.x + q1v.y); \
  const float q2 = reduce2(q2v.x + q2v.y); \
  const float a_ = __builtin_fmaf(64.0f, dCC, -2.0f * q1); \
  DS = __builtin_fmaf(dCC, a_, q2); }

// store z checkpoint: z = 0.05*U - 0.05*CC
#define STZ(k, p0, p1) { float4 zq; \
  zq.x = __builtin_fmaf(0.05f, U##p0.x, -CC05); \
  zq.y = __builtin_fmaf(0.05f, U##p0.y, -CC05); \
  zq.z = __builtin_fmaf(0.05f, U##p1.x, -CC05); \
  zq.w = __builtin_fmaf(0.05f, U##p1.y, -CC05); \
  *(float4*)(zst + base + 4 * (k)) = zq; }

// pass2: load z checkpoint, accumulate R partials
#define LOADZ(k, p0, p1) { \
  const float4 zq = *(const float4*)(zst + base + 4 * (k)); \
  U##p0.x = 20.0f * zq.x; U##p0.y = 20.0f * zq.y; \
  U##p1.x = 20.0f * zq.z; U##p1.y = 20.0f * zq.w; \
  r0 += zq.x + zq.y; r1 += zq.z + zq.w; }

// pass2: R += 0.05*c
#define RC(p) { r0 = __builtin_fmaf(-0.05f, nc##p.x, r0); \
  r1 = __builtin_fmaf(-0.05f, nc##p.y, r1); }

// final store: clamp(z, 0, 1)
#define STOUT(k, p0, p1) { float4 o; \
  o.x = __builtin_amdgcn_fmed3f( \
      __builtin_fmaf(0.05f, U##p0.x, -CC05), 0.0f, 1.0f); \
  o.y = __builtin_amdgcn_fmed3f( \
      __builtin_fmaf(0.05f, U##p0.y, -CC05), 0.0f, 1.0f); \
  o.z = __builtin_amdgcn_fmed3f( \
      __builtin_fmaf(0.05f, U##p1.x, -CC05), 0.0f, 1.0f); \
  o.w = __builtin_amdgcn_fmed3f( \
      __builtin_fmaf(0.05f, U##p1.y, -CC05), 0.0f, 1.0f); \
  *(float4*)(out + base + 4 * (k)) = o; }

// --- pass1: P unchecked iters, checked to wave all-pass; checkpoint --------
__global__ __attribute__((amdgpu_flat_work_group_size(256, 256),
                          amdgpu_waves_per_eu(4, 4)))
void dys_pass1(
    const float* __restrict__ cost, const int* __restrict__ Tsample,
    int* __restrict__ Tglob, int* __restrict__ TrArr,
    float* __restrict__ zst) {
  const int lane = threadIdx.x & 63;
  const int gw = blockIdx.x * 4 + (threadIdx.x >> 6);
  // lane pair owns one row; each lane holds 32 elems
  const int base = (gw * RPW_C + (lane >> 1)) * 64 + (lane & 1) * 32;

  const v2f K1p = {K1, K1};
  P16(DECL_STATE)
  PAIRS8(LOADC)
  float r0 = 0.0f, r1 = 0.0f;
  P16(INITU)
  float R = reduce2(r0 + r1);              // R = Sz + a*Sc over the row
  float CC = 0.0f;

  const int Ts = *Tsample;                 // uniform
  const int Pn = (Ts > 2) ? (Ts - 2) : 0;  // P+1 <= Ts <= T

  for (int i = 0; i < Pn; ++i) FAST_ITER();

  int ib = MAXIT;
  for (int i = Pn + 1; i <= MAXIT; ++i) {
    float ds;
    CHK_ITER(ds)
    if (__all(ds <= 0.04f)) { ib = i; break; }
  }
  // ib = max(Pn+1, wave-max Tr) <= T; the argmax wave reports exactly T.

  const float CC05 = 0.05f * CC;           // z = 0.05*U - 0.05*CC
  PAIRS8(STZ)
  if (lane == 0) {
    TrArr[gw] = ib;
    atomicMax(Tglob, ib);
  }
}

// --- pass2: resume ib -> T, +1 differentiable step, clamp, store -----------
__global__ __attribute__((amdgpu_flat_work_group_size(256, 256),
                          amdgpu_waves_per_eu(4, 4)))
void dys_pass2(
    const float* __restrict__ cost, const int* __restrict__ Tglob,
    const int* __restrict__ TrArr, const float* __restrict__ zst,
    float* __restrict__ out) {
  const int lane = threadIdx.x & 63;
  const int gw = blockIdx.x * 4 + (threadIdx.x >> 6);
  const int base = (gw * RPW_C + (lane >> 1)) * 64 + (lane & 1) * 32;

  const v2f K1p = {K1, K1};
  P16(DECL_STATE)
  PAIRS8(LOADC)
  float r0 = 0.0f, r1 = 0.0f;
  PAIRS8(LOADZ)
  P16(RC)
  float R = reduce2(r0 + r1);              // R = Sz + a*Sc (invariant)
  float CC = 0.0f;

  const int T = *Tglob;
  const int ib = TrArr[gw];                // wave-uniform

  // (T - ib) lockstep iters to z(T), +1 differentiable step
  for (int i = ib; i <= T; ++i) FAST_ITER();

  const float CC05 = 0.05f * CC;
  PAIRS8(STOUT)
}

extern "C" void kernel_launch(void* const* d_in, const int* in_sizes, int n_in,
                              void* d_out, int out_size, void* d_ws,
                              size_t ws_size, hipStream_t stream) {
  const float* cost = (const float*)d_in[0];
  float* out = (float*)d_out;

  // ws: [0..4) Tglob ; [4..8) Tsample ; [1024..) TrArr ; then z ckpt
  // (offsets kept from r10: TrArr region sized for 16384 ints, C uses 8192)
  int* Tglob   = (int*)d_ws;
  int* Tsample = (int*)d_ws + 1;
  const size_t TR_OFF = 1024;
  const size_t Z_OFF  = TR_OFF + (size_t)NWAVES_A * sizeof(int);  // 16B-aligned
  int*   TrArr = (int*)((char*)d_ws + TR_OFF);
  float* zst   = (float*)((char*)d_ws + Z_OFF);

  hipMemsetAsync(d_ws, 0, 8, stream);   // Tglob = Tsample = 0

  dim3 block(256);
  dys_probe<<<dim3(PROBE_WAVES / 4), block, 0, stream>>>(cost, Tsample);
  dys_pass1<<<dim3(NWAVES_C / 4), block, 0, stream>>>(cost, Tsample, Tglob,
                                                      TrArr, zst);
  dys_pass2<<<dim3(NWAVES_C / 4), block, 0, stream>>>(cost, Tglob, TrArr, zst,
                                                      out);
}